// Round 4
// baseline (308.715 us; speedup 1.0000x reference)
//
#include <hip/hip_runtime.h>
#include <hip/hip_bf16.h>

typedef unsigned short u16;
typedef unsigned int   u32;
typedef __attribute__((ext_vector_type(8)))  short s16x8;
typedef __attribute__((ext_vector_type(16))) float f32x16;
typedef __attribute__((ext_vector_type(4)))  unsigned short u16x4;

#define MT    8192   // B*S tokens
#define DE    2048   // embed dim
#define NEXP  64     // experts
#define ERDIM 4096   // experts * rank

// round-to-nearest-even f32 -> bf16
__device__ __forceinline__ u16 to_bf16(float f) {
  u32 u = __builtin_bit_cast(u32, f);
  u32 r = u + 0x7fffu + ((u >> 16) & 1u);
  return (u16)(r >> 16);
}

__global__ void cvt_f32_bf16(const float* __restrict__ in, u16* __restrict__ out, int n) {
  const int stride = gridDim.x * blockDim.x;
  for (int i = blockIdx.x * blockDim.x + threadIdx.x; i * 4 < n; i += stride) {
    const float4 v = *reinterpret_cast<const float4*>(in + (size_t)i * 4);
    u16x4 o;
    o.x = to_bf16(v.x); o.y = to_bf16(v.y); o.z = to_bf16(v.z); o.w = to_bf16(v.w);
    *reinterpret_cast<u16x4*>(out + (size_t)i * 4) = o;
  }
}

#define GLDS(gp, lp) __builtin_amdgcn_global_load_lds(                        \
    (const __attribute__((address_space(1))) void*)(gp),                      \
    (__attribute__((address_space(3))) void*)(lp), 16, 0, 0)

#define BAR() do { asm volatile("" ::: "memory");                             \
                   __builtin_amdgcn_s_barrier();                              \
                   asm volatile("" ::: "memory"); } while (0)

// C = A[M,K] * B[N,K]^T (bf16, row-major). 256x256 tile, BK=32, 8 waves (2Mx4N),
// 32x32x16 MFMA. 4-slot LDS ring, prefetch distance 3, counted vmcnt.
// Per-tile order: [frag ds_reads] [GLDS stage t+3] [vmcnt(8)] [barrier] [16 MFMA]
// -> ds_read latency absorbed by vmcnt+barrier slack; post-barrier is pure MFMA.
// Safety: reads(t) follow barrier(t-1) whose vmcnt guaranteed tile t landed
// (all waves waited, then synced); GLDS(t+3) targets slot (t-1)&3 whose readers
// finished before barrier(t-1).
// FUSE=1: C_bf16[m,n] = bf16( silu(acc) * mask[m, n>>6] );  FUSE=0: C_f32 = acc
template<int FUSE, int K>
__global__ __launch_bounds__(512, 2) void gemm_bt(
    const u16* __restrict__ A, const u16* __restrict__ Bm,
    const float* __restrict__ mask, void* __restrict__ Cout,
    const int M, const int N)
{
  constexpr int BM = 256, BN = 256, BK = 32;
  constexpr int NT = K / BK;
  __shared__ __align__(16) u16 lds[65536];   // 4 slots x (A 16KB + B 16KB)

  const int nbn = N / BN;
  const int nwg = (int)gridDim.x;
  const int cpx = nwg >> 3;
  const int bid = (int)blockIdx.x;
  const int swz = (bid & 7) * cpx + (bid >> 3);  // bijective XCD swizzle
  const int bm = (swz / nbn) * BM;
  const int bn = (swz % nbn) * BN;

  const int tid  = (int)threadIdx.x;
  const int lane = tid & 63;
  const int w    = tid >> 6;       // wave 0..7
  const int wr   = w >> 2;         // 0..1: M row-group (128 rows)
  const int wc   = w & 3;          // 0..3: N col-group (64 cols)

  const int l31 = lane & 31;
  // granule col within BK=32 (4 granules of 8 elems) for kstep ks:
  //   p(ks) = (2*ks + (lane>>5)) ^ ((lane>>1)&3);  p1 = p0 ^ 2
  const int p0 = (lane >> 5) ^ ((lane >> 1) & 3);
  const int p1 = p0 ^ 2;

  // within-slot elem offsets (A at 0, B at 8192)
  const int aO0 = (wr * 128 + l31) * 32 + p0 * 8;
  const int aO1 = (wr * 128 + l31) * 32 + p1 * 8;
  const int bO0 = 8192 + (wc * 64 + l31) * 32 + p0 * 8;
  const int bO1 = 8192 + (wc * 64 + l31) * 32 + p1 * 8;

  // staging: wave w owns chunks {2w, 2w+1} (16 rows x 64B) of A and B.
  // linear LDS dest + inverse-swizzled global source (granule involution).
  const int lr = lane >> 2;
  const int cl = (lane & 3) ^ ((lane >> 3) & 3);
  const int c0 = 2 * w, c1 = 2 * w + 1;
  const u16* aS0 = A  + (size_t)(bm + c0 * 16 + lr) * K + cl * 8;
  const u16* aS1 = A  + (size_t)(bm + c1 * 16 + lr) * K + cl * 8;
  const u16* bS0 = Bm + (size_t)(bn + c0 * 16 + lr) * K + cl * 8;
  const u16* bS1 = Bm + (size_t)(bn + c1 * 16 + lr) * K + cl * 8;

  f32x16 acc[4][2] = {};

  // ---- prologue: stage tiles 0,1,2 ----
#pragma unroll
  for (int t = 0; t < 3; ++t) {
    u16* dst = lds + t * 16384;
    GLDS(aS0 + t * BK, dst +        c0 * 512);
    GLDS(aS1 + t * BK, dst +        c1 * 512);
    GLDS(bS0 + t * BK, dst + 8192 + c0 * 512);
    GLDS(bS1 + t * BK, dst + 8192 + c1 * 512);
  }
  asm volatile("s_waitcnt vmcnt(8)" ::: "memory");   // tile 0 landed
  BAR();

  // ---- main loop ----
#pragma unroll 4
  for (int t = 0; t < NT; ++t) {
    const u16* sl = lds + (t & 3) * 16384;

    // [1] frag reads for tile t (12 x ds_read_b128)
    s16x8 a0[4], a1[4], b0[2], b1[2];
#pragma unroll
    for (int m = 0; m < 4; ++m) {
      a0[m] = *reinterpret_cast<const s16x8*>(&sl[aO0 + m * 1024]);
      a1[m] = *reinterpret_cast<const s16x8*>(&sl[aO1 + m * 1024]);
    }
#pragma unroll
    for (int n = 0; n < 2; ++n) {
      b0[n] = *reinterpret_cast<const s16x8*>(&sl[bO0 + n * 1024]);
      b1[n] = *reinterpret_cast<const s16x8*>(&sl[bO1 + n * 1024]);
    }

    // [2] stage tile t+3
    if (t + 3 < NT) {
      u16* dst = lds + ((t + 3) & 3) * 16384;
      const size_t koff = (size_t)(t + 3) * BK;
      GLDS(aS0 + koff, dst +        c0 * 512);
      GLDS(aS1 + koff, dst +        c1 * 512);
      GLDS(bS0 + koff, dst + 8192 + c0 * 512);
      GLDS(bS1 + koff, dst + 8192 + c1 * 512);
    }

    // [3] counted vmcnt: guarantee tile t+1 landed before its post-barrier reads
    if (t + 3 < NT)      asm volatile("s_waitcnt vmcnt(8)" ::: "memory");
    else if (t + 2 < NT) asm volatile("s_waitcnt vmcnt(4)" ::: "memory");
    else if (t + 1 < NT) asm volatile("s_waitcnt vmcnt(0)" ::: "memory");

    // [4] barrier: cross-wave landing guarantee + slot-reuse fence
    BAR();

    // [5] pure-MFMA phase (frags issued pre-barrier; lgkm wait nearly free)
    __builtin_amdgcn_s_setprio(1);
#pragma unroll
    for (int m = 0; m < 4; ++m)
#pragma unroll
      for (int n = 0; n < 2; ++n)
        acc[m][n] = __builtin_amdgcn_mfma_f32_32x32x16_bf16(
            a0[m], b0[n], acc[m][n], 0, 0, 0);
#pragma unroll
    for (int m = 0; m < 4; ++m)
#pragma unroll
      for (int n = 0; n < 2; ++n)
        acc[m][n] = __builtin_amdgcn_mfma_f32_32x32x16_bf16(
            a1[m], b1[n], acc[m][n], 0, 0, 0);
    __builtin_amdgcn_s_setprio(0);
  }

  // ---- epilogue: 32x32 C/D layout col=lane&31, row=(reg&3)+8*(reg>>2)+4*(lane>>5) ----
  const int rbase = 4 * (lane >> 5);
  if (FUSE) {
    u16* H = (u16*)Cout;
    const int ew = (bn + wc * 64) >> 6;  // wave's 64-col span = one expert
#pragma unroll
    for (int m = 0; m < 4; ++m) {
#pragma unroll
      for (int q = 0; q < 4; ++q) {
#pragma unroll
        for (int j = 0; j < 4; ++j) {
          const int grow = bm + wr * 128 + m * 32 + j + 8 * q + rbase;
          const float mv = mask[(size_t)grow * NEXP + ew];
#pragma unroll
          for (int n = 0; n < 2; ++n) {
            const int gcol = bn + wc * 64 + n * 32 + l31;
            float v = acc[m][n][q * 4 + j];
            v = v / (1.0f + __expf(-v));   // silu
            H[(size_t)grow * N + gcol] = to_bf16(v * mv);
          }
        }
      }
    }
  } else {
    float* O = (float*)Cout;
#pragma unroll
    for (int m = 0; m < 4; ++m) {
#pragma unroll
      for (int q = 0; q < 4; ++q) {
#pragma unroll
        for (int j = 0; j < 4; ++j) {
          const int grow = bm + wr * 128 + m * 32 + j + 8 * q + rbase;
#pragma unroll
          for (int n = 0; n < 2; ++n) {
            const int gcol = bn + wc * 64 + n * 32 + l31;
            O[(size_t)grow * N + gcol] = acc[m][n][q * 4 + j];
          }
        }
      }
    }
  }
}

extern "C" void kernel_launch(void* const* d_in, const int* in_sizes, int n_in,
                              void* d_out, int out_size, void* d_ws, size_t ws_size,
                              hipStream_t stream) {
  const float* x     = (const float*)d_in[0];
  const float* emask = (const float*)d_in[1];
  const float* w_up  = (const float*)d_in[2];
  const float* w_dn  = (const float*)d_in[3];
  float* out = (float*)d_out;

  // workspace (bf16): x[8192,2048] | w_up[4096,2048] | w_dn[2048,4096] | H[8192,4096]
  const size_t need = ((size_t)MT * DE + (size_t)ERDIM * DE + (size_t)DE * ERDIM +
                       (size_t)MT * ERDIM) * sizeof(u16);
  if (ws_size < need) return;

  u16* xb  = (u16*)d_ws;
  u16* wub = xb  + (size_t)MT * DE;
  u16* wdb = wub + (size_t)ERDIM * DE;
  u16* hb  = wdb + (size_t)DE * ERDIM;

  hipLaunchKernelGGL(cvt_f32_bf16, dim3(2048), dim3(256), 0, stream, x,    xb,  MT * DE);
  hipLaunchKernelGGL(cvt_f32_bf16, dim3(1024), dim3(256), 0, stream, w_up, wub, ERDIM * DE);
  hipLaunchKernelGGL(cvt_f32_bf16, dim3(1024), dim3(256), 0, stream, w_dn, wdb, DE * ERDIM);

  // GEMM1: H = silu(X @ Wup^T) * mask   [M=8192, N=4096, K=2048] -> 512 blocks
  hipLaunchKernelGGL((gemm_bt<1, DE>), dim3((MT / 256) * (ERDIM / 256)), dim3(512), 0, stream,
                     xb, wub, emask, (void*)hb, MT, ERDIM);
  // GEMM2: out = H @ Wdown^T             [M=8192, N=2048, K=4096] -> 256 blocks
  hipLaunchKernelGGL((gemm_bt<0, ERDIM>), dim3((MT / 256) * (DE / 256)), dim3(512), 0, stream,
                     hb, wdb, nullptr, (void*)out, MT, DE);
}